// Round 1
// baseline (2133.664 us; speedup 1.0000x reference)
//
#include <hip/hip_runtime.h>

#define C128 128

typedef __attribute__((ext_vector_type(4))) float f32x4;
typedef __attribute__((ext_vector_type(8))) short short8;

// f32 -> bf16 with round-to-nearest-even (finite inputs only)
__device__ __forceinline__ short f2bf(float f) {
  union { float f; unsigned u; } v; v.f = f;
  unsigned r = (v.u + 0x7fffu + ((v.u >> 16) & 1u)) >> 16;
  return (short)r;
}

// out[r][j] = sum_k (A[r][k] * inv_r) * W[j][k]  (+ add[r][j]) (+ gtab[gidx[r]][j])
// inv_r = 1/max(cnt[r],1) when cnt != nullptr, else 1.
// Tile: 64 rows x 128 cols per block; 4 waves, each wave owns 16 rows x 128 cols.
// MFMA 16x16x32 bf16. A-frag: row = lane&15, k = (lane>>4)*8 + i (8 consecutive f32).
// B[k][j] = W[j][k] -> b[i] = W[col][k0+i], col = lane&15 (contiguous in W row).
// D: col = lane&15, row = (lane>>4)*4 + reg.
__global__ __launch_bounds__(256) void gemm_wt_fused(
    const float* __restrict__ A, const float* __restrict__ W,
    const float* __restrict__ cnt, const float* __restrict__ add,
    const int* __restrict__ gidx, const float* __restrict__ gtab,
    float* __restrict__ out, int R)
{
  const int tid  = threadIdx.x;
  const int wave = tid >> 6;
  const int lane = tid & 63;
  const int r16  = lane & 15;
  const int kg   = lane >> 4;

  const int rowbase = blockIdx.x * 64 + wave * 16;
  const int arow_i  = rowbase + r16;
  const int lrow    = arow_i < R ? arow_i : (R - 1);  // clamp; garbage rows never stored

  float inv = 1.0f;
  if (cnt) {
    float c = cnt[lrow];
    inv = 1.0f / (c > 1.0f ? c : 1.0f);
  }

  f32x4 acc[8];
#pragma unroll
  for (int i = 0; i < 8; ++i) acc[i] = (f32x4){0.f, 0.f, 0.f, 0.f};

  const float* arow = A + (long long)lrow * C128;

#pragma unroll
  for (int ks = 0; ks < 4; ++ks) {
    const int k0 = ks * 32 + kg * 8;
    f32x4 alo = *(const f32x4*)(arow + k0);
    f32x4 ahi = *(const f32x4*)(arow + k0 + 4);
    short8 af;
    af[0] = f2bf(alo.x * inv); af[1] = f2bf(alo.y * inv);
    af[2] = f2bf(alo.z * inv); af[3] = f2bf(alo.w * inv);
    af[4] = f2bf(ahi.x * inv); af[5] = f2bf(ahi.y * inv);
    af[6] = f2bf(ahi.z * inv); af[7] = f2bf(ahi.w * inv);
#pragma unroll
    for (int nf = 0; nf < 8; ++nf) {
      const float* wrow = W + (nf * 16 + r16) * C128 + k0;
      f32x4 wlo = *(const f32x4*)(wrow);
      f32x4 whi = *(const f32x4*)(wrow + 4);
      short8 bf;
      bf[0] = f2bf(wlo.x); bf[1] = f2bf(wlo.y);
      bf[2] = f2bf(wlo.z); bf[3] = f2bf(wlo.w);
      bf[4] = f2bf(whi.x); bf[5] = f2bf(whi.y);
      bf[6] = f2bf(whi.z); bf[7] = f2bf(whi.w);
      acc[nf] = __builtin_amdgcn_mfma_f32_16x16x32_bf16(af, bf, acc[nf], 0, 0, 0);
    }
  }

#pragma unroll
  for (int i = 0; i < 4; ++i) {
    const int orow = rowbase + kg * 4 + i;
    if (orow >= R) continue;
    const float* addrow = add ? add + (long long)orow * C128 : nullptr;
    const float* grow = gidx ? gtab + (long long)gidx[orow] * C128 : nullptr;
    float* orow_p = out + (long long)orow * C128;
#pragma unroll
    for (int nf = 0; nf < 8; ++nf) {
      const int oc = nf * 16 + r16;
      float v = acc[nf][i];
      if (addrow) v += addrow[oc];
      if (grow)   v += grow[oc];
      orow_p[oc] = v;
    }
  }
}

// Fused streaming pass over x (N rows x 128): optionally y = x + gt[cl[row]],
// and always scatter-add x into sum[cl[row]] plus count.
// One thread handles one float4 (q = which float4 of the row, 0..31).
__global__ __launch_bounds__(256) void scatter_pass(
    const float* __restrict__ x, const int* __restrict__ cl,
    const float* __restrict__ gt, float* __restrict__ y,
    float* __restrict__ sum, float* __restrict__ cnt, long long nvec)
{
  long long i = (long long)blockIdx.x * blockDim.x + threadIdx.x;
  const long long stride = (long long)gridDim.x * blockDim.x;
  for (; i < nvec; i += stride) {
    const long long row = i >> 5;
    const int q = (int)(i & 31);
    const int c = cl[row];
    f32x4 xv = ((const f32x4*)x)[i];
    if (y) {
      f32x4 tv = ((const f32x4*)gt)[(long long)c * 32 + q];
      ((f32x4*)y)[i] = xv + tv;
    }
    float* s = sum + (long long)c * C128 + q * 4;
    unsafeAtomicAdd(s + 0, xv.x);
    unsafeAtomicAdd(s + 1, xv.y);
    unsafeAtomicAdd(s + 2, xv.z);
    unsafeAtomicAdd(s + 3, xv.w);
    if (q == 0) unsafeAtomicAdd(cnt + c, 1.0f);
  }
}

extern "C" void kernel_launch(void* const* d_in, const int* in_sizes, int n_in,
                              void* d_out, int out_size, void* d_ws, size_t ws_size,
                              hipStream_t stream)
{
  const float* x0 = (const float*)d_in[0];
  const float* x1 = (const float*)d_in[1];
  const float* x2 = (const float*)d_in[2];
  const int* cluster1 = (const int*)d_in[3];
  const int* cluster2 = (const int*)d_in[4];
  const float* Wf2c0 = (const float*)d_in[5];
  const float* Wf2c1 = (const float*)d_in[6];
  const float* Wc2f0 = (const float*)d_in[7];
  const float* Wc2f1 = (const float*)d_in[8];

  const int N0 = in_sizes[0] / C128;
  const int N1 = in_sizes[1] / C128;
  const int N2 = in_sizes[2] / C128;

  float* y0 = (float*)d_out;
  float* y1 = y0 + (long long)N0 * C128;
  float* y2 = y1 + (long long)N1 * C128;

  // workspace layout: [t1: N1*C][t2: N2*C][cnt0: N1][cnt1: N2][sum0: N1*C][sum1: N2*C]
  float* t1   = (float*)d_ws;
  float* t2   = t1 + (long long)N1 * C128;
  float* cnt0 = t2 + (long long)N2 * C128;
  float* cnt1 = cnt0 + N1;
  float* sum0 = cnt1 + N2;
  float* sum1 = sum0 + (long long)N1 * C128;

  const size_t need_full = (size_t)(2LL * N1 * C128 + 2LL * N2 * C128 + N1 + N2) * 4;
  const bool ws_sums = ws_size >= need_full;
  // Fallback: accumulate sums directly in the y1/y2 output regions (finalize GEMM
  // is in-place-safe: each wave reads only the 16 rows it later writes).
  float* sum0p = ws_sums ? sum0 : y1;
  float* sum1p = ws_sums ? sum1 : y2;

  // zero count + sum accumulators (every call: harness does not re-poison)
  hipMemsetAsync(cnt0, 0, (size_t)(N1 + N2) * 4, stream);
  if (ws_sums) {
    hipMemsetAsync(sum0, 0, (size_t)((long long)(N1 + N2) * C128) * 4, stream);
  } else {
    hipMemsetAsync(y1, 0, (size_t)((long long)(N1 + N2) * C128) * 4, stream);
  }

  // t1 = x1 @ Wc2f0^T ; t2 = x2 @ Wc2f1^T
  gemm_wt_fused<<<(N1 + 63) / 64, 256, 0, stream>>>(
      x1, Wc2f0, nullptr, nullptr, nullptr, nullptr, t1, N1);
  gemm_wt_fused<<<(N2 + 63) / 64, 256, 0, stream>>>(
      x2, Wc2f1, nullptr, nullptr, nullptr, nullptr, t2, N2);

  // fused big pass: y0 = x0 + t1[cluster1]; scatter x0 into sum0p/cnt0
  scatter_pass<<<4096, 256, 0, stream>>>(
      x0, cluster1, t1, y0, sum0p, cnt0, (long long)N0 * 32);
  // small pass: scatter x1 into sum1p/cnt1
  scatter_pass<<<1024, 256, 0, stream>>>(
      x1, cluster2, nullptr, nullptr, sum1p, cnt1, (long long)N1 * 32);

  // y1 = (sum0/max(cnt0,1)) @ Wf2c0^T + x1 + t2[cluster2]
  gemm_wt_fused<<<(N1 + 63) / 64, 256, 0, stream>>>(
      sum0p, Wf2c0, cnt0, x1, cluster2, t2, y1, N1);
  // y2 = (sum1/max(cnt1,1)) @ Wf2c1^T + x2
  gemm_wt_fused<<<(N2 + 63) / 64, 256, 0, stream>>>(
      sum1p, Wf2c1, cnt1, x2, nullptr, nullptr, y2, N2);
}

// Round 3
// 669.166 us; speedup vs baseline: 3.1885x; 3.1885x over previous
//
#include <hip/hip_runtime.h>

#define C128 128

typedef __attribute__((ext_vector_type(2))) float f32x2;
typedef __attribute__((ext_vector_type(4))) float f32x4;
typedef __attribute__((ext_vector_type(8))) short short8;

// f32 -> bf16 with round-to-nearest-even (finite inputs only)
__device__ __forceinline__ short f2bf(float f) {
  union { float f; unsigned u; } v; v.f = f;
  unsigned r = (v.u + 0x7fffu + ((v.u >> 16) & 1u)) >> 16;
  return (short)r;
}

// out[r][j] = sum_k A[r][k] * W[j][k]  (+ add[r][j]) (+ gtab[gidx[r]][j])
// Tile: 64 rows x 128 cols per block; 4 waves, each wave owns 16 rows x 128 cols.
// MFMA 16x16x32 bf16. A-frag: row = lane&15, k = (lane>>4)*8 + i.
// D: col = lane&15, row = (lane>>4)*4 + reg.
// In-place safe for out==A: each wave reads only the 16 rows it later writes,
// and all A reads precede all stores within the wave. (Overflow-row clamp reads
// are benign races on discarded data.)
__global__ __launch_bounds__(256) void gemm_wt_fused(
    const float* __restrict__ A, const float* __restrict__ W,
    const float* __restrict__ add,
    const int* __restrict__ gidx, const float* __restrict__ gtab,
    float* __restrict__ out, int R)
{
  const int tid  = threadIdx.x;
  const int wave = tid >> 6;
  const int lane = tid & 63;
  const int r16  = lane & 15;
  const int kg   = lane >> 4;

  const int rowbase = blockIdx.x * 64 + wave * 16;
  const int arow_i  = rowbase + r16;
  const int lrow    = arow_i < R ? arow_i : (R - 1);  // clamp; garbage rows never stored

  f32x4 acc[8];
#pragma unroll
  for (int i = 0; i < 8; ++i) acc[i] = (f32x4){0.f, 0.f, 0.f, 0.f};

  const float* arow = A + (long long)lrow * C128;

#pragma unroll
  for (int ks = 0; ks < 4; ++ks) {
    const int k0 = ks * 32 + kg * 8;
    f32x4 alo = *(const f32x4*)(arow + k0);
    f32x4 ahi = *(const f32x4*)(arow + k0 + 4);
    short8 af;
    af[0] = f2bf(alo.x); af[1] = f2bf(alo.y);
    af[2] = f2bf(alo.z); af[3] = f2bf(alo.w);
    af[4] = f2bf(ahi.x); af[5] = f2bf(ahi.y);
    af[6] = f2bf(ahi.z); af[7] = f2bf(ahi.w);
#pragma unroll
    for (int nf = 0; nf < 8; ++nf) {
      const float* wrow = W + (nf * 16 + r16) * C128 + k0;
      f32x4 wlo = *(const f32x4*)(wrow);
      f32x4 whi = *(const f32x4*)(wrow + 4);
      short8 bf;
      bf[0] = f2bf(wlo.x); bf[1] = f2bf(wlo.y);
      bf[2] = f2bf(wlo.z); bf[3] = f2bf(wlo.w);
      bf[4] = f2bf(whi.x); bf[5] = f2bf(whi.y);
      bf[6] = f2bf(whi.z); bf[7] = f2bf(whi.w);
      acc[nf] = __builtin_amdgcn_mfma_f32_16x16x32_bf16(af, bf, acc[nf], 0, 0, 0);
    }
  }

#pragma unroll
  for (int i = 0; i < 4; ++i) {
    const int orow = rowbase + kg * 4 + i;
    if (orow >= R) continue;
    const float* addrow = add ? add + (long long)orow * C128 : nullptr;
    const float* grow = gidx ? gtab + (long long)gidx[orow] * C128 : nullptr;
    float* orow_p = out + (long long)orow * C128;
#pragma unroll
    for (int nf = 0; nf < 8; ++nf) {
      const int oc = nf * 16 + r16;
      float v = acc[nf][i];
      if (addrow) v += addrow[oc];
      if (grow)   v += grow[oc];
      orow_p[oc] = v;
    }
  }
}

// histogram: cnt[cl[i]]++ (int atomics on L2-resident counters)
__global__ __launch_bounds__(256) void hist_kernel(
    const int* __restrict__ cl, int* __restrict__ cnt, int n)
{
  int i = blockIdx.x * blockDim.x + threadIdx.x;
  const int stride = gridDim.x * blockDim.x;
  for (; i < n; i += stride) atomicAdd(&cnt[cl[i]], 1);
}

// offsets via atomic cursor: ordering of segments is arbitrary but disjoint
// and consistent within one launch sequence (off/cur written together).
__global__ __launch_bounds__(256) void scan_kernel(
    const int* __restrict__ cnt, int* __restrict__ off, int* __restrict__ cur,
    int* __restrict__ tot, int n)
{
  int i = blockIdx.x * blockDim.x + threadIdx.x;
  if (i < n) {
    int c = cnt[i];
    int o = atomicAdd(tot, c);
    off[i] = o;
    cur[i] = o;
  }
}

// fill member lists: idx[cur[cl[i]]++] = i
__global__ __launch_bounds__(256) void fill_kernel(
    const int* __restrict__ cl, int* __restrict__ cur, int* __restrict__ idx, int n)
{
  int i = blockIdx.x * blockDim.x + threadIdx.x;
  const int stride = gridDim.x * blockDim.x;
  for (; i < n; i += stride) {
    int p = atomicAdd(&cur[cl[i]], 1);
    idx[p] = i;
  }
}

// One wave per cluster: gather member rows, accumulate in registers, write mean.
// FUSE_Y: also write y[i] = x[i] + t[cluster] (t row loaded once per wave).
// Lane owns columns {2*lane, 2*lane+1} (f32x2, 512B/row fully coalesced).
template<bool FUSE_Y>
__global__ __launch_bounds__(256) void cluster_reduce(
    const float* __restrict__ x, const int* __restrict__ idx,
    const int* __restrict__ off, const int* __restrict__ cnt,
    const float* __restrict__ t, float* __restrict__ y,
    float* __restrict__ mean, int nc)
{
  const int wid  = blockIdx.x * (blockDim.x >> 6) + (threadIdx.x >> 6);
  const int lane = threadIdx.x & 63;
  if (wid >= nc) return;

  const int n = cnt[wid];
  const int o = off[wid];

  f32x2 s = {0.f, 0.f};
  f32x2 tc = {0.f, 0.f};
  if (FUSE_Y) tc = ((const f32x2*)(t + (long long)wid * C128))[lane];

  for (int m = 0; m < n; ++m) {
    const int i = idx[o + m];
    f32x2 xv = ((const f32x2*)(x + (long long)i * C128))[lane];
    s += xv;
    if (FUSE_Y) ((f32x2*)(y + (long long)i * C128))[lane] = xv + tc;
  }

  const float invn = n > 0 ? 1.0f / (float)n : 0.0f;
  ((f32x2*)(mean + (long long)wid * C128))[lane] = s * invn;
}

extern "C" void kernel_launch(void* const* d_in, const int* in_sizes, int n_in,
                              void* d_out, int out_size, void* d_ws, size_t ws_size,
                              hipStream_t stream)
{
  const float* x0 = (const float*)d_in[0];
  const float* x1 = (const float*)d_in[1];
  const float* x2 = (const float*)d_in[2];
  const int* cluster1 = (const int*)d_in[3];
  const int* cluster2 = (const int*)d_in[4];
  const float* Wf2c0 = (const float*)d_in[5];
  const float* Wf2c1 = (const float*)d_in[6];
  const float* Wc2f0 = (const float*)d_in[7];
  const float* Wc2f1 = (const float*)d_in[8];

  const int N0 = in_sizes[0] / C128;
  const int N1 = in_sizes[1] / C128;
  const int N2 = in_sizes[2] / C128;

  float* y0 = (float*)d_out;
  float* y1 = y0 + (long long)N0 * C128;
  float* y2 = y1 + (long long)N1 * C128;

  // means live in-place in the output regions (finalize GEMM is in-place safe)
  float* mean0 = y1;
  float* mean1 = y2;

  // workspace layout (4B units):
  // [t1: N1*128][t2: N2*128][cnt0: N1][cnt1: N2][tot: 2][off0: N1][off1: N2]
  // [cur0: N1][cur1: N2][idx0: N0][idx1: N1]   (~61.5 MB total)
  float* t1 = (float*)d_ws;
  float* t2 = t1 + (long long)N1 * C128;
  int* cnt0 = (int*)(t2 + (long long)N2 * C128);
  int* cnt1 = cnt0 + N1;
  int* tot  = cnt1 + N2;           // 2 counters
  int* off0 = tot + 2;
  int* off1 = off0 + N1;
  int* cur0 = off1 + N2;
  int* cur1 = cur0 + N1;
  int* idx0 = cur1 + N2;
  int* idx1 = idx0 + N0;

  // zero cnt0, cnt1, tot (contiguous)
  hipMemsetAsync(cnt0, 0, (size_t)(N1 + N2 + 2) * 4, stream);

  // t1 = x1 @ Wc2f0^T ; t2 = x2 @ Wc2f1^T  (independent of CSR build)
  gemm_wt_fused<<<(N1 + 63) / 64, 256, 0, stream>>>(
      x1, Wc2f0, nullptr, nullptr, nullptr, t1, N1);
  gemm_wt_fused<<<(N2 + 63) / 64, 256, 0, stream>>>(
      x2, Wc2f1, nullptr, nullptr, nullptr, t2, N2);

  // CSR build for cluster1 (N0 -> N1) and cluster2 (N1 -> N2)
  {
    int b0 = (N0 + 255) / 256; if (b0 > 2048) b0 = 2048;
    int b1 = (N1 + 255) / 256; if (b1 > 2048) b1 = 2048;
    hist_kernel<<<b0, 256, 0, stream>>>(cluster1, cnt0, N0);
    hist_kernel<<<b1, 256, 0, stream>>>(cluster2, cnt1, N1);
    scan_kernel<<<(N1 + 255) / 256, 256, 0, stream>>>(cnt0, off0, cur0, tot + 0, N1);
    scan_kernel<<<(N2 + 255) / 256, 256, 0, stream>>>(cnt1, off1, cur1, tot + 1, N2);
    fill_kernel<<<b0, 256, 0, stream>>>(cluster1, cur0, idx0, N0);
    fill_kernel<<<b1, 256, 0, stream>>>(cluster2, cur1, idx1, N1);
  }

  // ONE WAVE PER CLUSTER: nc waves = nc*64 threads = (nc+3)/4 blocks of 256.
  // (R2 bug: launched nc/64 waves -> 94% of y0 never written.)
  // big fused pass: y0 = x0 + t1[cluster1] and mean0 = segment_mean(x0)
  cluster_reduce<true><<<(N1 + 3) / 4, 256, 0, stream>>>(
      x0, idx0, off0, cnt0, t1, y0, mean0, N1);
  // small pass: mean1 = segment_mean(x1)
  cluster_reduce<false><<<(N2 + 3) / 4, 256, 0, stream>>>(
      x1, idx1, off1, cnt1, nullptr, nullptr, mean1, N2);

  // y1 = mean0 @ Wf2c0^T + x1 + t2[cluster2]   (in-place: A == out == y1 region)
  gemm_wt_fused<<<(N1 + 63) / 64, 256, 0, stream>>>(
      mean0, Wf2c0, x1, cluster2, t2, y1, N1);
  // y2 = mean1 @ Wf2c1^T + x2                   (in-place: A == out == y2 region)
  gemm_wt_fused<<<(N2 + 63) / 64, 256, 0, stream>>>(
      mean1, Wf2c1, x2, nullptr, nullptr, y2, N2);
}